// Round 5
// baseline (854.242 us; speedup 1.0000x reference)
//
#include <hip/hip_runtime.h>
#include <hip/hip_bf16.h>
#include <math.h>

// ---------------------------------------------------------------------------
// FuncGNN R17 (= R16 with the nontemporal float4 compile fix):
// - Dense kernels: 8-way LDS bank conflicts on A^T scalar column writes
//   (gin_fuse measured SQ_LDS_BANK_CONFLICT=3.4M) replaced by 4x4 register
//   transpose + contiguous float4 LDS writes.
// - gather64: payload/xprev/rdeg/out marked nontemporal (via clang
//   ext_vector_type(4) float, since __builtin_nontemporal_* rejects
//   HIP_vector_type) so streamed data stops evicting valb rows from L2.
// ---------------------------------------------------------------------------

#define NBSHIFT 9           // 512 nodes per bucket
#define NBSIZE  512

typedef float vf4 __attribute__((ext_vector_type(4)));

__device__ __forceinline__ float gelu_f(float x) {
    return 0.5f * x * (1.0f + erff(x * 0.70710678118654752440f));
}
__device__ __forceinline__ unsigned short f2bf(float x) {
    __hip_bfloat16 h = __float2bfloat16(x);      // RNE
    return *reinterpret_cast<unsigned short*>(&h);
}
__device__ __forceinline__ unsigned pack2bf(float a, float b) {
    return (unsigned)f2bf(a) | ((unsigned)f2bf(b) << 16);
}
__device__ __forceinline__ float bf2f(unsigned short u) {
    return __uint_as_float((unsigned)u << 16);
}

// ------------- gemm64: Cb[n,64](bf16) = A @ Wa + ba  (p=0 only) --------------
__global__ __launch_bounds__(256) void gemm64(
    const float* __restrict__ A,
    const float* __restrict__ Wa, const float* __restrict__ ba,
    unsigned short* __restrict__ Cb, int n)
{
    __shared__ __align__(16) float At[64][68];
    __shared__ __align__(16) float Ws[64][68];
    const int tid = threadIdx.x;
    const int tx = tid & 15, ty = tid >> 4;
    const int rowBase = blockIdx.x * 64;
    const int ty4 = ty * 4;

    // ---- staging: 4x4 register transpose, float4 LDS writes (no conflicts)
    {
        float4 R[4];
        #pragma unroll
        for (int i = 0; i < 4; ++i) {
            int grow = rowBase + ty4 + i;
            R[i] = make_float4(0.f, 0.f, 0.f, 0.f);
            if (grow < n) R[i] = *(const float4*)(A + (size_t)grow * 64 + tx * 4);
        }
        #pragma unroll
        for (int j = 0; j < 4; ++j) {
            float4 c = make_float4(((const float*)&R[0])[j],
                                   ((const float*)&R[1])[j],
                                   ((const float*)&R[2])[j],
                                   ((const float*)&R[3])[j]);
            *(float4*)&At[tx * 4 + j][ty4] = c;
        }
        #pragma unroll
        for (int i = 0; i < 4; ++i) {
            int v = tid + i * 256;
            int r = v >> 4, k4 = (v & 15) * 4;
            *(float4*)&Ws[r][k4] = *(const float4*)(Wa + r * 64 + k4);
        }
    }
    __syncthreads();

    const int r0 = ty * 4, c0 = tx * 4;
    float acc[4][4];
    #pragma unroll
    for (int j = 0; j < 4; ++j) {
        float bv = ba[c0 + j];
        #pragma unroll
        for (int i = 0; i < 4; ++i) acc[i][j] = bv;
    }
    #pragma unroll 16
    for (int k = 0; k < 64; ++k) {
        float4 av = *(const float4*)&At[k][r0];
        float4 wv = *(const float4*)&Ws[k][c0];
        float a4[4] = {av.x, av.y, av.z, av.w};
        float w4[4] = {wv.x, wv.y, wv.z, wv.w};
        #pragma unroll
        for (int i = 0; i < 4; ++i)
            #pragma unroll
            for (int j = 0; j < 4; ++j)
                acc[i][j] = fmaf(a4[i], w4[j], acc[i][j]);
    }
    #pragma unroll
    for (int i = 0; i < 4; ++i) {
        int grow = rowBase + r0 + i;
        if (grow < n) {
            uint2 u;
            u.x = pack2bf(acc[i][0], acc[i][1]);
            u.y = pack2bf(acc[i][2], acc[i][3]);
            *(uint2*)(Cb + (size_t)grow * 64 + c0) = u;
        }
    }
}

// -- act_fuse: graph-norm scale/offset in-block; x=gelu(h*a+b) (bf16 only);
//    xfinal (+)= x @ Wf (+bf if FIRST) ---------------------------------------
template<bool FIRST>
__global__ __launch_bounds__(256) void act_fuse(
    const float* __restrict__ h,
    const float* __restrict__ colsum, const float* __restrict__ colsumsq,
    const float* __restrict__ nw, const float* __restrict__ nb,
    const float* __restrict__ rsw, const float* __restrict__ rsb,
    const float* __restrict__ rbw, const float* __restrict__ rbb,
    const float* __restrict__ rate_p, float inv_n,
    const float* __restrict__ Wf, const float* __restrict__ bf,
    unsigned short* __restrict__ xb, float* __restrict__ xfinal, int n)
{
    __shared__ __align__(16) float At[64][68];
    __shared__ __align__(16) float Ws[64][68];
    __shared__ float ab_s[128];
    const int tid = threadIdx.x;
    const int tx = tid & 15, ty = tid >> 4;
    const int rowBase = blockIdx.x * 64;
    const int ty4 = ty * 4;

    if (tid < 64) {
        float mean = colsum[tid] * inv_n;
        float var  = colsumsq[tid] * inv_n - mean * mean;
        float rstd = rsqrtf(var + 1e-5f);
        float rate = rate_p[0];
        float gamma = nw[tid] + (rsw[tid] * rate + rsb[tid]);
        float beta  = nb[tid] + (rbw[tid] * rate + rbb[tid]);
        float a = rstd * gamma;
        ab_s[tid] = a;
        ab_s[64 + tid] = beta - mean * a;
    }
    __syncthreads();

    {
        const float s0 = ab_s[tx * 4 + 0], s1 = ab_s[tx * 4 + 1];
        const float s2 = ab_s[tx * 4 + 2], s3 = ab_s[tx * 4 + 3];
        const float o0 = ab_s[64 + tx * 4 + 0], o1 = ab_s[64 + tx * 4 + 1];
        const float o2 = ab_s[64 + tx * 4 + 2], o3 = ab_s[64 + tx * 4 + 3];
        float4 R[4];
        #pragma unroll
        for (int i = 0; i < 4; ++i) {
            int grow = rowBase + ty4 + i;
            float4 a = make_float4(0.f, 0.f, 0.f, 0.f);
            if (grow < n) {
                float4 hv = *(const float4*)(h + (size_t)grow * 64 + tx * 4);
                a.x = gelu_f(fmaf(hv.x, s0, o0));
                a.y = gelu_f(fmaf(hv.y, s1, o1));
                a.z = gelu_f(fmaf(hv.z, s2, o2));
                a.w = gelu_f(fmaf(hv.w, s3, o3));
                uint2 u;
                u.x = pack2bf(a.x, a.y);
                u.y = pack2bf(a.z, a.w);
                *(uint2*)(xb + (size_t)grow * 64 + tx * 4) = u;
            }
            R[i] = a;
        }
        #pragma unroll
        for (int j = 0; j < 4; ++j) {
            float4 c = make_float4(((const float*)&R[0])[j],
                                   ((const float*)&R[1])[j],
                                   ((const float*)&R[2])[j],
                                   ((const float*)&R[3])[j]);
            *(float4*)&At[tx * 4 + j][ty4] = c;
        }
        #pragma unroll
        for (int i = 0; i < 4; ++i) {
            int v = tid + i * 256;
            int r = v >> 4, k4 = (v & 15) * 4;
            *(float4*)&Ws[r][k4] = *(const float4*)(Wf + r * 64 + k4);
        }
    }
    __syncthreads();

    const int r0 = ty * 4, c0 = tx * 4;
    float acc[4][4];
    if (FIRST) {
        #pragma unroll
        for (int j = 0; j < 4; ++j) {
            float bv = bf[c0 + j];
            #pragma unroll
            for (int i = 0; i < 4; ++i) acc[i][j] = bv;
        }
    } else {
        #pragma unroll
        for (int i = 0; i < 4; ++i)
            #pragma unroll
            for (int j = 0; j < 4; ++j) acc[i][j] = 0.f;
    }
    #pragma unroll 16
    for (int k = 0; k < 64; ++k) {
        float4 av = *(const float4*)&At[k][r0];
        float4 wv = *(const float4*)&Ws[k][c0];
        float a4[4] = {av.x, av.y, av.z, av.w};
        float w4[4] = {wv.x, wv.y, wv.z, wv.w};
        #pragma unroll
        for (int i = 0; i < 4; ++i)
            #pragma unroll
            for (int j = 0; j < 4; ++j)
                acc[i][j] = fmaf(a4[i], w4[j], acc[i][j]);
    }
    #pragma unroll
    for (int i = 0; i < 4; ++i) {
        int grow = rowBase + r0 + i;
        if (grow < n) {
            float4 r = make_float4(acc[i][0], acc[i][1], acc[i][2], acc[i][3]);
            float* cp = xfinal + (size_t)grow * 64 + c0;
            if (!FIRST) {
                float4 c = *(const float4*)cp;
                r.x += c.x; r.y += c.y; r.z += c.z; r.w += c.w;
            }
            *(float4*)cp = r;
        }
    }
}

// -- gin_fuse: t=gelu(z@W1+b1); o=t@W2+b2 -> xout; xfinal += o@Wf;
//    if NEXT: bfout = bf16(o @ Wn + bn)   (next pair's SAGE xt) --------------
template<bool NEXT>
__global__ __launch_bounds__(256) void gin_fuse(
    const float* __restrict__ z,
    const float* __restrict__ W1, const float* __restrict__ b1,
    const float* __restrict__ W2, const float* __restrict__ b2,
    const float* __restrict__ Wf,
    const float* __restrict__ Wn, const float* __restrict__ bn,
    float* __restrict__ xout, float* __restrict__ xfinal,
    unsigned short* __restrict__ bfout, int n)
{
    __shared__ __align__(16) float At[64][68];
    __shared__ __align__(16) float Ws[64][68];
    const int tid = threadIdx.x;
    const int tx = tid & 15, ty = tid >> 4;
    const int rowBase = blockIdx.x * 64;
    const int r0 = ty * 4, c0 = tx * 4;
    const int ty4 = ty * 4;

    {
        float4 R[4];
        #pragma unroll
        for (int i = 0; i < 4; ++i) {
            int grow = rowBase + ty4 + i;
            R[i] = make_float4(0.f, 0.f, 0.f, 0.f);
            if (grow < n) R[i] = *(const float4*)(z + (size_t)grow * 64 + tx * 4);
        }
        #pragma unroll
        for (int j = 0; j < 4; ++j) {
            float4 c = make_float4(((const float*)&R[0])[j],
                                   ((const float*)&R[1])[j],
                                   ((const float*)&R[2])[j],
                                   ((const float*)&R[3])[j]);
            *(float4*)&At[tx * 4 + j][ty4] = c;
        }
        #pragma unroll
        for (int i = 0; i < 4; ++i) {
            int v = tid + i * 256;
            int r = v >> 4, k4 = (v & 15) * 4;
            *(float4*)&Ws[r][k4] = *(const float4*)(W1 + r * 64 + k4);
        }
    }
    __syncthreads();

    float acc[4][4];
    #pragma unroll
    for (int j = 0; j < 4; ++j) {
        float bv = b1[c0 + j];
        #pragma unroll
        for (int i = 0; i < 4; ++i) acc[i][j] = bv;
    }
    #pragma unroll 16
    for (int k = 0; k < 64; ++k) {
        float4 av = *(const float4*)&At[k][r0];
        float4 wv = *(const float4*)&Ws[k][c0];
        float a4[4] = {av.x, av.y, av.z, av.w};
        float w4[4] = {wv.x, wv.y, wv.z, wv.w};
        #pragma unroll
        for (int i = 0; i < 4; ++i)
            #pragma unroll
            for (int j = 0; j < 4; ++j)
                acc[i][j] = fmaf(a4[i], w4[j], acc[i][j]);
    }

    // ---- GEMM2: gelu(acc) @ W2 + b2   (float4 transpose write)
    __syncthreads();
    #pragma unroll
    for (int j = 0; j < 4; ++j) {
        float4 c = make_float4(gelu_f(acc[0][j]), gelu_f(acc[1][j]),
                               gelu_f(acc[2][j]), gelu_f(acc[3][j]));
        *(float4*)&At[c0 + j][r0] = c;
    }
    #pragma unroll
    for (int i = 0; i < 4; ++i) {
        int v = tid + i * 256;
        int k = v >> 4, c4 = (v & 15) * 4;
        *(float4*)&Ws[k][c4] = *(const float4*)(W2 + k * 64 + c4);
    }
    __syncthreads();
    float acc2[4][4];
    #pragma unroll
    for (int j = 0; j < 4; ++j) {
        float bv = b2[c0 + j];
        #pragma unroll
        for (int i = 0; i < 4; ++i) acc2[i][j] = bv;
    }
    #pragma unroll 16
    for (int k = 0; k < 64; ++k) {
        float4 av = *(const float4*)&At[k][r0];
        float4 wv = *(const float4*)&Ws[k][c0];
        float a4[4] = {av.x, av.y, av.z, av.w};
        float w4[4] = {wv.x, wv.y, wv.z, wv.w};
        #pragma unroll
        for (int i = 0; i < 4; ++i)
            #pragma unroll
            for (int j = 0; j < 4; ++j)
                acc2[i][j] = fmaf(a4[i], w4[j], acc2[i][j]);
    }
    #pragma unroll
    for (int i = 0; i < 4; ++i) {
        int grow = rowBase + r0 + i;
        if (grow < n)
            *(float4*)(xout + (size_t)grow * 64 + c0) =
                make_float4(acc2[i][0], acc2[i][1], acc2[i][2], acc2[i][3]);
    }

    // ---- GEMM3: xfinal += acc2 @ Wf   (At <- acc2^T via float4; reused by GEMM4)
    __syncthreads();
    #pragma unroll
    for (int j = 0; j < 4; ++j) {
        float4 c = make_float4(acc2[0][j], acc2[1][j], acc2[2][j], acc2[3][j]);
        *(float4*)&At[c0 + j][r0] = c;
    }
    #pragma unroll
    for (int i = 0; i < 4; ++i) {
        int v = tid + i * 256;
        int k = v >> 4, c4 = (v & 15) * 4;
        *(float4*)&Ws[k][c4] = *(const float4*)(Wf + k * 64 + c4);
    }
    __syncthreads();
    float acc3[4][4];
    #pragma unroll
    for (int i = 0; i < 4; ++i)
        #pragma unroll
        for (int j = 0; j < 4; ++j) acc3[i][j] = 0.f;
    #pragma unroll 16
    for (int k = 0; k < 64; ++k) {
        float4 av = *(const float4*)&At[k][r0];
        float4 wv = *(const float4*)&Ws[k][c0];
        float a4[4] = {av.x, av.y, av.z, av.w};
        float w4[4] = {wv.x, wv.y, wv.z, wv.w};
        #pragma unroll
        for (int i = 0; i < 4; ++i)
            #pragma unroll
            for (int j = 0; j < 4; ++j)
                acc3[i][j] = fmaf(a4[i], w4[j], acc3[i][j]);
    }
    #pragma unroll
    for (int i = 0; i < 4; ++i) {
        int grow = rowBase + r0 + i;
        if (grow < n) {
            float* cp = xfinal + (size_t)grow * 64 + c0;
            float4 c = *(const float4*)cp;
            c.x += acc3[i][0]; c.y += acc3[i][1];
            c.z += acc3[i][2]; c.w += acc3[i][3];
            *(float4*)cp = c;
        }
    }

    if (NEXT) {
        // ---- GEMM4: bfout = bf16(acc2 @ Wn + bn); At still holds acc2^T
        __syncthreads();
        #pragma unroll
        for (int i = 0; i < 4; ++i) {
            int v = tid + i * 256;
            int k = v >> 4, c4 = (v & 15) * 4;
            *(float4*)&Ws[k][c4] = *(const float4*)(Wn + k * 64 + c4);
        }
        __syncthreads();
        float acc4[4][4];
        #pragma unroll
        for (int j = 0; j < 4; ++j) {
            float bv = bn[c0 + j];
            #pragma unroll
            for (int i = 0; i < 4; ++i) acc4[i][j] = bv;
        }
        #pragma unroll 16
        for (int k = 0; k < 64; ++k) {
            float4 av = *(const float4*)&At[k][r0];
            float4 wv = *(const float4*)&Ws[k][c0];
            float a4[4] = {av.x, av.y, av.z, av.w};
            float w4[4] = {wv.x, wv.y, wv.z, wv.w};
            #pragma unroll
            for (int i = 0; i < 4; ++i)
                #pragma unroll
                for (int j = 0; j < 4; ++j)
                    acc4[i][j] = fmaf(a4[i], w4[j], acc4[i][j]);
        }
        #pragma unroll
        for (int i = 0; i < 4; ++i) {
            int grow = rowBase + r0 + i;
            if (grow < n) {
                uint2 u;
                u.x = pack2bf(acc4[i][0], acc4[i][1]);
                u.y = pack2bf(acc4[i][2], acc4[i][3]);
                *(uint2*)(bfout + (size_t)grow * 64 + c0) = u;
            }
        }
    }
}

// ---------------- bucket-sorted CSR build ------------------------------------
__global__ void init_buckets(int* __restrict__ bucket_cursor, int Bn, int cap) {
    int t = threadIdx.x;
    if (t < Bn) bucket_cursor[t] = t * cap;
}

__global__ __launch_bounds__(256) void bucketA(
    const int* __restrict__ eidx, int* __restrict__ bucket_cursor,
    uint2* __restrict__ inter, int E)
{
    __shared__ int cnt[256], lo[256], cur[256], garr[256];
    __shared__ int tot_s;
    __shared__ uint2 stage[4096];
    const int tid = threadIdx.x;
    cnt[tid] = 0;
    __syncthreads();

    const int base = blockIdx.x * 4096;
    int pay[16], dfull[16];
    #pragma unroll
    for (int i = 0; i < 16; ++i) {
        int e = base + i * 256 + tid;
        dfull[i] = -1;
        if (e < E) {
            int s  = __builtin_nontemporal_load(eidx + e * 3 + 0);
            int d  = __builtin_nontemporal_load(eidx + e * 3 + 1);
            int sg = __builtin_nontemporal_load(eidx + e * 3 + 2);
            if (sg < 0) s |= 0x80000000;
            pay[i] = s;
            dfull[i] = d;
            atomicAdd(&cnt[d >> NBSHIFT], 1);
        }
    }
    __syncthreads();

    lo[tid] = cnt[tid];
    __syncthreads();
    for (int off = 1; off < 256; off <<= 1) {
        int t = (tid >= off) ? lo[tid - off] : 0;
        __syncthreads();
        lo[tid] += t;
        __syncthreads();
    }
    if (tid == 255) tot_s = lo[255];
    int excl = lo[tid] - cnt[tid];
    __syncthreads();
    lo[tid] = excl;
    cur[tid] = 0;
    if (cnt[tid] > 0) garr[tid] = atomicAdd(bucket_cursor + tid, cnt[tid]);
    __syncthreads();

    #pragma unroll
    for (int i = 0; i < 16; ++i) {
        if (dfull[i] >= 0) {
            int k = dfull[i] >> NBSHIFT;
            int r = atomicAdd(&cur[k], 1);
            stage[lo[k] + r] = make_uint2((unsigned)pay[i], (unsigned)dfull[i]);
        }
    }
    __syncthreads();

    const int tot = tot_s;
    for (int i = tid; i < tot; i += 256) {
        uint2 en = stage[i];
        int k = (int)(en.y >> NBSHIFT);
        inter[garr[k] + (i - lo[k])] = en;
    }
}

__global__ __launch_bounds__(256) void bucketB1(
    const uint2* __restrict__ inter, const int* __restrict__ bucket_cursor,
    int* __restrict__ deg_i, int cap, int n)
{
    __shared__ int cnt[NBSIZE];
    const int b = blockIdx.x, tid = threadIdx.x;
    cnt[tid] = 0; cnt[tid + 256] = 0;
    __syncthreads();
    const int base = b * cap;
    const int len = bucket_cursor[b] - base;
    for (int i = tid; i < len; i += 256)
        atomicAdd(&cnt[inter[base + i].y & (NBSIZE - 1)], 1);
    __syncthreads();
    const int nb0 = b << NBSHIFT;
    if (nb0 + tid < n)       deg_i[nb0 + tid]       = cnt[tid];
    if (nb0 + 256 + tid < n) deg_i[nb0 + 256 + tid] = cnt[256 + tid];
}

__global__ __launch_bounds__(256) void bucketB2(
    const uint2* __restrict__ inter, const int* __restrict__ bucket_cursor,
    const int* __restrict__ row_ptr, int* __restrict__ payload, int cap, int n)
{
    __shared__ int cur[NBSIZE];
    const int b = blockIdx.x, tid = threadIdx.x;
    const int nb0 = b << NBSHIFT;
    cur[tid]       = (nb0 + tid < n)       ? row_ptr[nb0 + tid]       : 0;
    cur[tid + 256] = (nb0 + 256 + tid < n) ? row_ptr[nb0 + 256 + tid] : 0;
    __syncthreads();
    const int base = b * cap;
    const int len = bucket_cursor[b] - base;
    for (int i = tid; i < len; i += 256) {
        uint2 en = inter[base + i];
        int pos = atomicAdd(&cur[en.y & (NBSIZE - 1)], 1);
        payload[pos] = (int)en.x;
    }
}

// ---------------- scans ------------------------------------------------------
__global__ __launch_bounds__(256) void scan1(
    const int* __restrict__ deg_i, int* __restrict__ blocksum, int n, int chunk)
{
    int b = blockIdx.x;
    int lo = b * chunk, hi = min(lo + chunk, n);
    int s = 0;
    for (int i = lo + (int)threadIdx.x; i < hi; i += 256) s += deg_i[i];
    #pragma unroll
    for (int off = 32; off; off >>= 1) s += __shfl_xor(s, off, 64);
    __shared__ int ws[4];
    if ((threadIdx.x & 63) == 0) ws[threadIdx.x >> 6] = s;
    __syncthreads();
    if (threadIdx.x == 0) blocksum[b] = ws[0] + ws[1] + ws[2] + ws[3];
}

__global__ __launch_bounds__(256) void scan2(
    const int* __restrict__ blocksum, int* __restrict__ blockoff,
    int* __restrict__ row_ptr_n)
{
    int tid = threadIdx.x, lane = tid & 63, wid = tid >> 6;
    int orig = blocksum[tid];
    int v = orig;
    #pragma unroll
    for (int off = 1; off < 64; off <<= 1) {
        int t = __shfl_up(v, off, 64);
        if (lane >= off) v += t;
    }
    __shared__ int wt[4];
    if (lane == 63) wt[wid] = v;
    __syncthreads();
    int woff = 0;
    for (int w = 0; w < wid; ++w) woff += wt[w];
    blockoff[tid] = woff + v - orig;
    if (tid == 255) *row_ptr_n = woff + v;
}

__global__ __launch_bounds__(256) void scan3(
    const int* __restrict__ deg_i, const int* __restrict__ blockoff,
    int* __restrict__ row_ptr, float* __restrict__ rdeg, int n, int chunk)
{
    int b = blockIdx.x;
    int lo = b * chunk, hi = min(lo + chunk, n);
    int carry = blockoff[b];
    int tid = threadIdx.x, lane = tid & 63, wid = tid >> 6;
    __shared__ int wt[4];
    for (int base = lo; base < hi; base += 256) {
        int i = base + tid;
        int orig = (i < hi) ? deg_i[i] : 0;
        int v = orig;
        #pragma unroll
        for (int off = 1; off < 64; off <<= 1) {
            int t = __shfl_up(v, off, 64);
            if (lane >= off) v += t;
        }
        if (lane == 63) wt[wid] = v;
        __syncthreads();
        int woff = 0;
        for (int w = 0; w < wid; ++w) woff += wt[w];
        int tot = wt[0] + wt[1] + wt[2] + wt[3];
        int excl = carry + woff + (v - orig);
        if (i < hi) {
            row_ptr[i] = excl;
            rdeg[i]    = 1.0f / ((float)orig + 1.0f);
        }
        carry += tot;
        __syncthreads();
    }
}

// ------- gather R15+nt: 8 nodes/wave (8-lane group per node), lane-private
//         accumulation, uniform trip count, 4-deep edge unroll; streaming
//         accesses (payload/xprev/rdeg/out) nontemporal to protect valb in L2.
__device__ __forceinline__ void accum8(float* a, uint4 u, float s) {
    a[0] = fmaf(__uint_as_float(u.x << 16),          s, a[0]);
    a[1] = fmaf(__uint_as_float(u.x & 0xffff0000u),  s, a[1]);
    a[2] = fmaf(__uint_as_float(u.y << 16),          s, a[2]);
    a[3] = fmaf(__uint_as_float(u.y & 0xffff0000u),  s, a[3]);
    a[4] = fmaf(__uint_as_float(u.z << 16),          s, a[4]);
    a[5] = fmaf(__uint_as_float(u.z & 0xffff0000u),  s, a[5]);
    a[6] = fmaf(__uint_as_float(u.w << 16),          s, a[6]);
    a[7] = fmaf(__uint_as_float(u.w & 0xffff0000u),  s, a[7]);
}

template<bool SAGE>
__global__ __launch_bounds__(256) void gather64(
    const int* __restrict__ row_ptr, const int* __restrict__ payload,
    const unsigned short* __restrict__ valb, const float* __restrict__ xprev,
    const float* __restrict__ rdeg, float* __restrict__ out,
    float* __restrict__ colsum, float* __restrict__ colsumsq, int n)
{
    const int tid  = threadIdx.x;
    const int lane = tid & 63;
    const int j8   = lane & 7;           // col sub-slot
    const int c0   = j8 * 8;             // cols [c0, c0+8)
    const int wid  = tid >> 6;
    const int gg0  = (blockIdx.x * 256 + tid) >> 3;   // global group id
    const int ng   = (gridDim.x * 256) >> 3;          // total groups

    float st[8], st2[8];
    if (SAGE) {
        #pragma unroll
        for (int k = 0; k < 8; ++k) { st[k] = 0.f; st2[k] = 0.f; }
    }

    for (int node = gg0; __any(node < n); node += ng) {
        const bool active  = node < n;
        const int  selfrow = active ? node : 0;
        const int  beg     = active ? row_ptr[node]     : 0;
        const int  end     = active ? row_ptr[node + 1] : 0;

        // wave-uniform trip count = max over the 8 groups
        int t = (end - beg + 3) >> 2;
        t = max(t, __shfl_xor(t, 8, 64));
        t = max(t, __shfl_xor(t, 16, 64));
        t = max(t, __shfl_xor(t, 32, 64));

        float a[8];
        #pragma unroll
        for (int k = 0; k < 8; ++k) a[k] = 0.f;

        // prefetch payload quad for it=0 (nontemporal: streamed once)
        int p0 = (beg + 0 < end) ? __builtin_nontemporal_load(payload + beg + 0) : 0;
        int p1 = (beg + 1 < end) ? __builtin_nontemporal_load(payload + beg + 1) : 0;
        int p2 = (beg + 2 < end) ? __builtin_nontemporal_load(payload + beg + 2) : 0;
        int p3 = (beg + 3 < end) ? __builtin_nontemporal_load(payload + beg + 3) : 0;

        for (int it = 0; it < t; ++it) {
            const int i0 = beg + (it << 2);
            const bool w0 = i0 + 0 < end, w1 = i0 + 1 < end;
            const bool w2 = i0 + 2 < end, w3 = i0 + 3 < end;
            const int q0 = p0, q1 = p1, q2 = p2, q3 = p3;

            // issue 4 independent row loads (8 rows per instr across groups)
            const int r0 = w0 ? (q0 & 0x7fffffff) : selfrow;
            const int r1 = w1 ? (q1 & 0x7fffffff) : selfrow;
            const int r2 = w2 ? (q2 & 0x7fffffff) : selfrow;
            const int r3 = w3 ? (q3 & 0x7fffffff) : selfrow;
            uint4 u0 = *(const uint4*)(valb + (size_t)r0 * 64 + c0);
            uint4 u1 = *(const uint4*)(valb + (size_t)r1 * 64 + c0);
            uint4 u2 = *(const uint4*)(valb + (size_t)r2 * 64 + c0);
            uint4 u3 = *(const uint4*)(valb + (size_t)r3 * 64 + c0);

            // prefetch next iteration's payload quad while rows are in flight
            const int nb = i0 + 4;
            p0 = (nb + 0 < end) ? __builtin_nontemporal_load(payload + nb + 0) : 0;
            p1 = (nb + 1 < end) ? __builtin_nontemporal_load(payload + nb + 1) : 0;
            p2 = (nb + 2 < end) ? __builtin_nontemporal_load(payload + nb + 2) : 0;
            p3 = (nb + 3 < end) ? __builtin_nontemporal_load(payload + nb + 3) : 0;

            const float s0 = w0 ? ((SAGE && q0 < 0) ? -1.f : 1.f) : 0.f;
            const float s1 = w1 ? ((SAGE && q1 < 0) ? -1.f : 1.f) : 0.f;
            const float s2 = w2 ? ((SAGE && q2 < 0) ? -1.f : 1.f) : 0.f;
            const float s3 = w3 ? ((SAGE && q3 < 0) ? -1.f : 1.f) : 0.f;
            accum8(a, u0, s0);
            accum8(a, u1, s1);
            accum8(a, u2, s2);
            accum8(a, u3, s3);
        }

        // self row (xt for SAGE, x for GIN)
        uint4 us = *(const uint4*)(valb + (size_t)selfrow * 64 + c0);
        accum8(a, us, 1.f);

        if (SAGE) {
            const float rd = active ? __builtin_nontemporal_load(rdeg + node) : 0.f;
            vf4 xp0 = __builtin_nontemporal_load(
                (const vf4*)(xprev + (size_t)selfrow * 64 + c0));
            vf4 xp1 = __builtin_nontemporal_load(
                (const vf4*)(xprev + (size_t)selfrow * 64 + c0 + 4));
            float xp[8] = {xp0.x, xp0.y, xp0.z, xp0.w,
                           xp1.x, xp1.y, xp1.z, xp1.w};
            float h[8];
            #pragma unroll
            for (int k = 0; k < 8; ++k) h[k] = fmaf(a[k], rd, xp[k]);
            if (active) {
                #pragma unroll
                for (int k = 0; k < 8; ++k) {
                    st[k]  += h[k];
                    st2[k] += h[k] * h[k];
                }
                vf4 o0 = {h[0], h[1], h[2], h[3]};
                vf4 o1 = {h[4], h[5], h[6], h[7]};
                __builtin_nontemporal_store(o0, (vf4*)(out + (size_t)node * 64 + c0));
                __builtin_nontemporal_store(o1, (vf4*)(out + (size_t)node * 64 + c0 + 4));
            }
        } else {
            if (active) {
                vf4 o0 = {a[0], a[1], a[2], a[3]};
                vf4 o1 = {a[4], a[5], a[6], a[7]};
                __builtin_nontemporal_store(o0, (vf4*)(out + (size_t)node * 64 + c0));
                __builtin_nontemporal_store(o1, (vf4*)(out + (size_t)node * 64 + c0 + 4));
            }
        }
    }

    if (SAGE) {
        // fold the 8 groups (lane-xor 8/16/32); each j8-class ends identical
        #pragma unroll
        for (int k = 0; k < 8; ++k) {
            st[k]  += __shfl_xor(st[k], 8, 64);
            st[k]  += __shfl_xor(st[k], 16, 64);
            st[k]  += __shfl_xor(st[k], 32, 64);
            st2[k] += __shfl_xor(st2[k], 8, 64);
            st2[k] += __shfl_xor(st2[k], 16, 64);
            st2[k] += __shfl_xor(st2[k], 32, 64);
        }
        __shared__ float sh[2][4][64];
        if (lane < 8) {
            #pragma unroll
            for (int k = 0; k < 8; ++k) {
                sh[0][wid][c0 + k] = st[k];
                sh[1][wid][c0 + k] = st2[k];
            }
        }
        __syncthreads();
        if (tid < 64) {
            float a_ = sh[0][0][tid] + sh[0][1][tid] + sh[0][2][tid] + sh[0][3][tid];
            float b_ = sh[1][0][tid] + sh[1][1][tid] + sh[1][2][tid] + sh[1][3][tid];
            atomicAdd(colsum + tid, a_);
            atomicAdd(colsumsq + tid, b_);
        }
    }
}

// ---------------- readout stage 1: H = relu(LN(x @ W1 + b1)) -----------------
__global__ __launch_bounds__(256) void readout1(
    const float* __restrict__ xf, const float* __restrict__ W1,
    const float* __restrict__ b1, const float* __restrict__ g1,
    const float* __restrict__ bt1, float* __restrict__ H, int n)
{
    __shared__ __align__(16) float At[64][68];
    __shared__ __align__(16) float Ws[64][132];
    const int tid = threadIdx.x;
    const int tx = tid & 15, ty = tid >> 4;
    const int rowBase = blockIdx.x * 64;
    const int ty4 = ty * 4;

    {
        float4 R[4];
        #pragma unroll
        for (int i = 0; i < 4; ++i) {
            int grow = rowBase + ty4 + i;
            R[i] = make_float4(0.f, 0.f, 0.f, 0.f);
            if (grow < n) R[i] = *(const float4*)(xf + (size_t)grow * 64 + tx * 4);
        }
        #pragma unroll
        for (int j = 0; j < 4; ++j) {
            float4 c = make_float4(((const float*)&R[0])[j],
                                   ((const float*)&R[1])[j],
                                   ((const float*)&R[2])[j],
                                   ((const float*)&R[3])[j]);
            *(float4*)&At[tx * 4 + j][ty4] = c;
        }
    }
    #pragma unroll
    for (int i = 0; i < 8; ++i) {
        int v = tid + i * 256;
        int k = v >> 5, c4 = (v & 31) * 4;
        *(float4*)&Ws[k][c4] = *(const float4*)(W1 + k * 128 + c4);
    }
    __syncthreads();

    const int r0 = ty * 4, c0 = tx * 8;
    float acc[4][8];
    #pragma unroll
    for (int j = 0; j < 8; ++j) {
        float bv = b1[c0 + j];
        #pragma unroll
        for (int i = 0; i < 4; ++i) acc[i][j] = bv;
    }
    #pragma unroll 8
    for (int k = 0; k < 64; ++k) {
        float4 av = *(const float4*)&At[k][r0];
        float4 w0 = *(const float4*)&Ws[k][c0];
        float4 w1v = *(const float4*)&Ws[k][c0 + 4];
        float a4[4] = {av.x, av.y, av.z, av.w};
        float w8[8] = {w0.x, w0.y, w0.z, w0.w, w1v.x, w1v.y, w1v.z, w1v.w};
        #pragma unroll
        for (int i = 0; i < 4; ++i)
            #pragma unroll
            for (int j = 0; j < 8; ++j)
                acc[i][j] = fmaf(a4[i], w8[j], acc[i][j]);
    }

    float gj[8], bj[8];
    #pragma unroll
    for (int j = 0; j < 8; ++j) { gj[j] = g1[c0 + j]; bj[j] = bt1[c0 + j]; }
    #pragma unroll
    for (int i = 0; i < 4; ++i) {
        int grow = rowBase + r0 + i;
        float s = 0.f, s2 = 0.f;
        #pragma unroll
        for (int j = 0; j < 8; ++j) { s += acc[i][j]; s2 += acc[i][j] * acc[i][j]; }
        #pragma unroll
        for (int off = 8; off; off >>= 1) {
            s  += __shfl_xor(s, off, 16);
            s2 += __shfl_xor(s2, off, 16);
        }
        float mean = s * (1.f / 128.f);
        float var  = s2 * (1.f / 128.f) - mean * mean;
        float rstd = rsqrtf(var + 1e-5f);
        float o[8];
        #pragma unroll
        for (int j = 0; j < 8; ++j)
            o[j] = fmaxf(fmaf((acc[i][j] - mean) * rstd, gj[j], bj[j]), 0.f);
        if (grow < n) {
            *(float4*)(H + (size_t)grow * 128 + c0)     = make_float4(o[0], o[1], o[2], o[3]);
            *(float4*)(H + (size_t)grow * 128 + c0 + 4) = make_float4(o[4], o[5], o[6], o[7]);
        }
    }
}

// ------- readout stage 2: prob = sigmoid(relu(LN(H @ W2 + b2)) @ W3 + b3) ----
__global__ __launch_bounds__(256) void readout2(
    const float* __restrict__ H, const float* __restrict__ W2,
    const float* __restrict__ b2, const float* __restrict__ g2,
    const float* __restrict__ bt2, const float* __restrict__ W3,
    const float* __restrict__ b3, float* __restrict__ prob, int n)
{
    __shared__ __align__(16) float Ht[64][68];
    __shared__ __align__(16) float Ws[64][132];
    const int tid = threadIdx.x;
    const int tx = tid & 15, ty = tid >> 4;
    const int rowBase = blockIdx.x * 64;
    const int r0 = ty * 4, c0 = tx * 8;
    const int ty4 = ty * 4;

    float acc[4][8];
    #pragma unroll
    for (int j = 0; j < 8; ++j) {
        float bv = b2[c0 + j];
        #pragma unroll
        for (int i = 0; i < 4; ++i) acc[i][j] = bv;
    }

    for (int kc = 0; kc < 2; ++kc) {
        if (kc) __syncthreads();
        {
            float4 R[4];
            #pragma unroll
            for (int i = 0; i < 4; ++i) {
                int grow = rowBase + ty4 + i;
                R[i] = make_float4(0.f, 0.f, 0.f, 0.f);
                if (grow < n)
                    R[i] = *(const float4*)(H + (size_t)grow * 128 + kc * 64 + tx * 4);
            }
            #pragma unroll
            for (int j = 0; j < 4; ++j) {
                float4 c = make_float4(((const float*)&R[0])[j],
                                       ((const float*)&R[1])[j],
                                       ((const float*)&R[2])[j],
                                       ((const float*)&R[3])[j]);
                *(float4*)&Ht[tx * 4 + j][ty4] = c;
            }
        }
        #pragma unroll
        for (int i = 0; i < 8; ++i) {
            int v = tid + i * 256;
            int k = v >> 5, c4 = (v & 31) * 4;
            *(float4*)&Ws[k][c4] = *(const float4*)(W2 + (kc * 64 + k) * 128 + c4);
        }
        __syncthreads();
        #pragma unroll 8
        for (int k = 0; k < 64; ++k) {
            float4 av = *(const float4*)&Ht[k][r0];
            float4 w0 = *(const float4*)&Ws[k][c0];
            float4 w1v = *(const float4*)&Ws[k][c0 + 4];
            float a4[4] = {av.x, av.y, av.z, av.w};
            float w8[8] = {w0.x, w0.y, w0.z, w0.w, w1v.x, w1v.y, w1v.z, w1v.w};
            #pragma unroll
            for (int i = 0; i < 4; ++i)
                #pragma unroll
                for (int j = 0; j < 8; ++j)
                    acc[i][j] = fmaf(a4[i], w8[j], acc[i][j]);
        }
    }

    float gj[8], bj[8], w3[8];
    #pragma unroll
    for (int j = 0; j < 8; ++j) {
        gj[j] = g2[c0 + j]; bj[j] = bt2[c0 + j]; w3[j] = W3[c0 + j];
    }
    const float bias3 = b3[0];
    #pragma unroll
    for (int i = 0; i < 4; ++i) {
        int grow = rowBase + r0 + i;
        float s = 0.f, s2 = 0.f;
        #pragma unroll
        for (int j = 0; j < 8; ++j) { s += acc[i][j]; s2 += acc[i][j] * acc[i][j]; }
        #pragma unroll
        for (int off = 8; off; off >>= 1) {
            s  += __shfl_xor(s, off, 16);
            s2 += __shfl_xor(s2, off, 16);
        }
        float mean = s * (1.f / 128.f);
        float var  = s2 * (1.f / 128.f) - mean * mean;
        float rstd = rsqrtf(var + 1e-5f);
        float d = 0.f;
        #pragma unroll
        for (int j = 0; j < 8; ++j) {
            float v = fmaxf(fmaf((acc[i][j] - mean) * rstd, gj[j], bj[j]), 0.f);
            d = fmaf(v, w3[j], d);
        }
        #pragma unroll
        for (int off = 8; off; off >>= 1) d += __shfl_xor(d, off, 16);
        if (tx == 0 && grow < n)
            prob[grow] = 1.f / (1.f + expf(-(d + bias3)));
    }
}

// ---------------------------------------------------------------------------
extern "C" void kernel_launch(void* const* d_in, const int* in_sizes, int n_in,
                              void* d_out, int out_size, void* d_ws, size_t ws_size,
                              hipStream_t stream)
{
    const float* init_emb = (const float*)d_in[0];
    const int*   eidx     = (const int*)d_in[1];
    const float* rate_b   = (const float*)d_in[2];
    const float* sage_W   = (const float*)d_in[3];
    const float* sage_b   = (const float*)d_in[4];
    const float* norm_w   = (const float*)d_in[5];
    const float* norm_b   = (const float*)d_in[6];
    const float* rs_w     = (const float*)d_in[7];
    const float* rs_b     = (const float*)d_in[8];
    const float* rb_w     = (const float*)d_in[9];
    const float* rb_b     = (const float*)d_in[10];
    const float* gin_W1   = (const float*)d_in[11];
    const float* gin_b1   = (const float*)d_in[12];
    const float* gin_W2   = (const float*)d_in[13];
    const float* gin_b2   = (const float*)d_in[14];
    const float* fuse_W   = (const float*)d_in[15];
    const float* fuse_b   = (const float*)d_in[16];
    const float* ro_W1    = (const float*)d_in[17];
    const float* ro_b1    = (const float*)d_in[18];
    const float* ln1_g    = (const float*)d_in[19];
    const float* ln1_b    = (const float*)d_in[20];
    const float* ro_W2    = (const float*)d_in[21];
    const float* ro_b2    = (const float*)d_in[22];
    const float* ln2_g    = (const float*)d_in[23];
    const float* ln2_b    = (const float*)d_in[24];
    const float* ro_W3    = (const float*)d_in[25];
    const float* ro_b3    = (const float*)d_in[26];

    const int N = in_sizes[0] / 64;
    const int E = in_sizes[1] / 3;
    const size_t nf = (size_t)N * 64;

    float* bufA  = (float*)d_ws;             // H region (with bufB) at readout
    float* bufB  = bufA + nf;
    float* bufC  = bufB + nf;
    unsigned short* bfbuf = (unsigned short*)(bufC + nf);  // nf bf16
    float* rdeg  = (float*)(bfbuf + nf);     // N floats
    float* stats = rdeg + N;                 // 3 x (colsum64|colsumsq64|pad)
    int*   row_ptr  = (int*)(stats + 3 * 256);   // N+1
    int*   deg_i    = row_ptr + (N + 1);         // N
    int*   blocksum = deg_i + N;                 // 256
    int*   blockoff = blocksum + 256;            // 256
    int*   bucket_cursor = blockoff + 256;       // <=256
    int*   payload  = bucket_cursor + 256;       // E
    uint2* inter    = (uint2*)bufC;              // aliases bufC (dead until p=1)

    float* xfinal = (float*)d_out;           // N x 64
    float* prob   = xfinal + nf;             // N
    float* H      = bufA;                    // N x 128 (bufA+bufB)

    const int gemm_blocks = (N + 63) / 64;
    const int gather_blocks = 2048;
    const int chunk  = (N + 255) / 256;
    const float inv_n = 1.0f / (float)N;

    const int Bn   = (N + NBSIZE - 1) / NBSIZE;
    const int meanb = (E + Bn - 1) / Bn;
    const int cap  = meanb + meanb / 8 + 64;
    const int ablocks = (E + 4095) / 4096;

    // ---- CSR build (bucket-sorted, deterministic) ----
    hipMemsetAsync(stats, 0, 3 * 256 * sizeof(float), stream);
    init_buckets<<<1, 256, 0, stream>>>(bucket_cursor, Bn, cap);
    bucketA<<<ablocks, 256, 0, stream>>>(eidx, bucket_cursor, inter, E);
    bucketB1<<<Bn, 256, 0, stream>>>(inter, bucket_cursor, deg_i, cap, N);
    scan1<<<256, 256, 0, stream>>>(deg_i, blocksum, N, chunk);
    scan2<<<1, 256, 0, stream>>>(blocksum, blockoff, row_ptr + N);
    scan3<<<256, 256, 0, stream>>>(deg_i, blockoff, row_ptr, rdeg, N, chunk);
    bucketB2<<<Bn, 256, 0, stream>>>(inter, bucket_cursor, row_ptr, payload, cap, N);

    for (int p = 0; p < 3; ++p) {
        const float* Xp = (p == 0) ? init_emb : (p == 1 ? (const float*)bufB : (const float*)bufC);
        float* B2p = (p == 1) ? bufC : bufB;
        float* cs = stats + p * 256;

        // 1. bfbuf = bf16(Xp @ W + b): explicit GEMM only for p=0; pairs 1,2
        //    get bfbuf from the previous gin_fuse's fused GEMM4.
        if (p == 0)
            gemm64<<<gemm_blocks, 256, 0, stream>>>(
                Xp, sage_W, sage_b, bfbuf, N);
        // 2. B2p = (xt + sum sign*xt[src]) * rdeg + Xp ; column stats
        gather64<true><<<gather_blocks, 256, 0, stream>>>(
            row_ptr, payload, bfbuf, Xp, rdeg, B2p, cs, cs + 64, N);
        // 3. bfbuf = bf16(gelu(norm(h))); xfinal (+)= x @ fuse_W[2p]
        if (p == 0)
            act_fuse<true><<<gemm_blocks, 256, 0, stream>>>(
                B2p, cs, cs + 64,
                norm_w + p * 64, norm_b + p * 64, rs_w + p * 64, rs_b + p * 64,
                rb_w + p * 64, rb_b + p * 64, rate_b, inv_n,
                fuse_W, fuse_b, bfbuf, xfinal, N);
        else
            act_fuse<false><<<gemm_blocks, 256, 0, stream>>>(
                B2p, cs, cs + 64,
                norm_w + p * 64, norm_b + p * 64, rs_w + p * 64, rs_b + p * 64,
                rb_w + p * 64, rb_b + p * 64, rate_b, inv_n,
                fuse_W + (2 * p) * 4096, nullptr, bfbuf, xfinal, N);
        // 4. B2p = x + sum x[src]   (z, from bf16 x copy)
        gather64<false><<<gather_blocks, 256, 0, stream>>>(
            row_ptr, payload, bfbuf, nullptr, nullptr, B2p, nullptr, nullptr, N);
        // 5. gin: B2p = gelu(z@W1+b1)@W2+b2 ; xfinal += B2p@fuse ;
        //    p<2: bfbuf = bf16(B2p @ sage_W[p+1] + sage_b[p+1])
        if (p < 2)
            gin_fuse<true><<<gemm_blocks, 256, 0, stream>>>(
                B2p, gin_W1 + p * 4096, gin_b1 + p * 64,
                gin_W2 + p * 4096, gin_b2 + p * 64,
                fuse_W + (2 * p + 1) * 4096,
                sage_W + (p + 1) * 4096, sage_b + (p + 1) * 64,
                B2p, xfinal, bfbuf, N);
        else
            gin_fuse<false><<<gemm_blocks, 256, 0, stream>>>(
                B2p, gin_W1 + p * 4096, gin_b1 + p * 64,
                gin_W2 + p * 4096, gin_b2 + p * 64,
                fuse_W + (2 * p + 1) * 4096,
                nullptr, nullptr, B2p, xfinal, nullptr, N);
    }

    // ---- readout ----
    readout1<<<gemm_blocks, 256, 0, stream>>>(
        xfinal, ro_W1, ro_b1, ln1_g, ln1_b, H, N);
    readout2<<<gemm_blocks, 256, 0, stream>>>(
        H, ro_W2, ro_b2, ln2_g, ln2_b, ro_W3, ro_b3, prob, N);
}

// Round 6
// 813.520 us; speedup vs baseline: 1.0501x; 1.0501x over previous
//
#include <hip/hip_runtime.h>
#include <hip/hip_bf16.h>
#include <math.h>

// ---------------------------------------------------------------------------
// FuncGNN R18:
// - gather: nt-hints REVERTED (R17 post-mortem: nt stores on B2p evicted data
//   the next dense kernel reads; nt payload loads bypassed useful L1 reuse;
//   net -25us). NEW: row loads software-pipelined one quad ahead (u=current,
//   v=next in flight) -> 8 rows in flight steady-state vs 4.
// - gin_fuse<false> (p=2): xout store skipped (dead -- overwritten by H
//   before any read).
// - Dense-kernel 4x4 register-transpose staging kept from R17 (conflicts
//   3.4M->1.8M; neutral on time, strictly less LDS traffic).
// ---------------------------------------------------------------------------

#define NBSHIFT 9           // 512 nodes per bucket
#define NBSIZE  512

__device__ __forceinline__ float gelu_f(float x) {
    return 0.5f * x * (1.0f + erff(x * 0.70710678118654752440f));
}
__device__ __forceinline__ unsigned short f2bf(float x) {
    __hip_bfloat16 h = __float2bfloat16(x);      // RNE
    return *reinterpret_cast<unsigned short*>(&h);
}
__device__ __forceinline__ unsigned pack2bf(float a, float b) {
    return (unsigned)f2bf(a) | ((unsigned)f2bf(b) << 16);
}
__device__ __forceinline__ float bf2f(unsigned short u) {
    return __uint_as_float((unsigned)u << 16);
}

// ------------- gemm64: Cb[n,64](bf16) = A @ Wa + ba  (p=0 only) --------------
__global__ __launch_bounds__(256) void gemm64(
    const float* __restrict__ A,
    const float* __restrict__ Wa, const float* __restrict__ ba,
    unsigned short* __restrict__ Cb, int n)
{
    __shared__ __align__(16) float At[64][68];
    __shared__ __align__(16) float Ws[64][68];
    const int tid = threadIdx.x;
    const int tx = tid & 15, ty = tid >> 4;
    const int rowBase = blockIdx.x * 64;
    const int ty4 = ty * 4;

    {
        float4 R[4];
        #pragma unroll
        for (int i = 0; i < 4; ++i) {
            int grow = rowBase + ty4 + i;
            R[i] = make_float4(0.f, 0.f, 0.f, 0.f);
            if (grow < n) R[i] = *(const float4*)(A + (size_t)grow * 64 + tx * 4);
        }
        #pragma unroll
        for (int j = 0; j < 4; ++j) {
            float4 c = make_float4(((const float*)&R[0])[j],
                                   ((const float*)&R[1])[j],
                                   ((const float*)&R[2])[j],
                                   ((const float*)&R[3])[j]);
            *(float4*)&At[tx * 4 + j][ty4] = c;
        }
        #pragma unroll
        for (int i = 0; i < 4; ++i) {
            int v = tid + i * 256;
            int r = v >> 4, k4 = (v & 15) * 4;
            *(float4*)&Ws[r][k4] = *(const float4*)(Wa + r * 64 + k4);
        }
    }
    __syncthreads();

    const int r0 = ty * 4, c0 = tx * 4;
    float acc[4][4];
    #pragma unroll
    for (int j = 0; j < 4; ++j) {
        float bv = ba[c0 + j];
        #pragma unroll
        for (int i = 0; i < 4; ++i) acc[i][j] = bv;
    }
    #pragma unroll 16
    for (int k = 0; k < 64; ++k) {
        float4 av = *(const float4*)&At[k][r0];
        float4 wv = *(const float4*)&Ws[k][c0];
        float a4[4] = {av.x, av.y, av.z, av.w};
        float w4[4] = {wv.x, wv.y, wv.z, wv.w};
        #pragma unroll
        for (int i = 0; i < 4; ++i)
            #pragma unroll
            for (int j = 0; j < 4; ++j)
                acc[i][j] = fmaf(a4[i], w4[j], acc[i][j]);
    }
    #pragma unroll
    for (int i = 0; i < 4; ++i) {
        int grow = rowBase + r0 + i;
        if (grow < n) {
            uint2 u;
            u.x = pack2bf(acc[i][0], acc[i][1]);
            u.y = pack2bf(acc[i][2], acc[i][3]);
            *(uint2*)(Cb + (size_t)grow * 64 + c0) = u;
        }
    }
}

// -- act_fuse: graph-norm scale/offset in-block; x=gelu(h*a+b) (bf16 only);
//    xfinal (+)= x @ Wf (+bf if FIRST) ---------------------------------------
template<bool FIRST>
__global__ __launch_bounds__(256) void act_fuse(
    const float* __restrict__ h,
    const float* __restrict__ colsum, const float* __restrict__ colsumsq,
    const float* __restrict__ nw, const float* __restrict__ nb,
    const float* __restrict__ rsw, const float* __restrict__ rsb,
    const float* __restrict__ rbw, const float* __restrict__ rbb,
    const float* __restrict__ rate_p, float inv_n,
    const float* __restrict__ Wf, const float* __restrict__ bf,
    unsigned short* __restrict__ xb, float* __restrict__ xfinal, int n)
{
    __shared__ __align__(16) float At[64][68];
    __shared__ __align__(16) float Ws[64][68];
    __shared__ float ab_s[128];
    const int tid = threadIdx.x;
    const int tx = tid & 15, ty = tid >> 4;
    const int rowBase = blockIdx.x * 64;
    const int ty4 = ty * 4;

    if (tid < 64) {
        float mean = colsum[tid] * inv_n;
        float var  = colsumsq[tid] * inv_n - mean * mean;
        float rstd = rsqrtf(var + 1e-5f);
        float rate = rate_p[0];
        float gamma = nw[tid] + (rsw[tid] * rate + rsb[tid]);
        float beta  = nb[tid] + (rbw[tid] * rate + rbb[tid]);
        float a = rstd * gamma;
        ab_s[tid] = a;
        ab_s[64 + tid] = beta - mean * a;
    }
    __syncthreads();

    {
        const float s0 = ab_s[tx * 4 + 0], s1 = ab_s[tx * 4 + 1];
        const float s2 = ab_s[tx * 4 + 2], s3 = ab_s[tx * 4 + 3];
        const float o0 = ab_s[64 + tx * 4 + 0], o1 = ab_s[64 + tx * 4 + 1];
        const float o2 = ab_s[64 + tx * 4 + 2], o3 = ab_s[64 + tx * 4 + 3];
        float4 R[4];
        #pragma unroll
        for (int i = 0; i < 4; ++i) {
            int grow = rowBase + ty4 + i;
            float4 a = make_float4(0.f, 0.f, 0.f, 0.f);
            if (grow < n) {
                float4 hv = *(const float4*)(h + (size_t)grow * 64 + tx * 4);
                a.x = gelu_f(fmaf(hv.x, s0, o0));
                a.y = gelu_f(fmaf(hv.y, s1, o1));
                a.z = gelu_f(fmaf(hv.z, s2, o2));
                a.w = gelu_f(fmaf(hv.w, s3, o3));
                uint2 u;
                u.x = pack2bf(a.x, a.y);
                u.y = pack2bf(a.z, a.w);
                *(uint2*)(xb + (size_t)grow * 64 + tx * 4) = u;
            }
            R[i] = a;
        }
        #pragma unroll
        for (int j = 0; j < 4; ++j) {
            float4 c = make_float4(((const float*)&R[0])[j],
                                   ((const float*)&R[1])[j],
                                   ((const float*)&R[2])[j],
                                   ((const float*)&R[3])[j]);
            *(float4*)&At[tx * 4 + j][ty4] = c;
        }
        #pragma unroll
        for (int i = 0; i < 4; ++i) {
            int v = tid + i * 256;
            int r = v >> 4, k4 = (v & 15) * 4;
            *(float4*)&Ws[r][k4] = *(const float4*)(Wf + r * 64 + k4);
        }
    }
    __syncthreads();

    const int r0 = ty * 4, c0 = tx * 4;
    float acc[4][4];
    if (FIRST) {
        #pragma unroll
        for (int j = 0; j < 4; ++j) {
            float bv = bf[c0 + j];
            #pragma unroll
            for (int i = 0; i < 4; ++i) acc[i][j] = bv;
        }
    } else {
        #pragma unroll
        for (int i = 0; i < 4; ++i)
            #pragma unroll
            for (int j = 0; j < 4; ++j) acc[i][j] = 0.f;
    }
    #pragma unroll 16
    for (int k = 0; k < 64; ++k) {
        float4 av = *(const float4*)&At[k][r0];
        float4 wv = *(const float4*)&Ws[k][c0];
        float a4[4] = {av.x, av.y, av.z, av.w};
        float w4[4] = {wv.x, wv.y, wv.z, wv.w};
        #pragma unroll
        for (int i = 0; i < 4; ++i)
            #pragma unroll
            for (int j = 0; j < 4; ++j)
                acc[i][j] = fmaf(a4[i], w4[j], acc[i][j]);
    }
    #pragma unroll
    for (int i = 0; i < 4; ++i) {
        int grow = rowBase + r0 + i;
        if (grow < n) {
            float4 r = make_float4(acc[i][0], acc[i][1], acc[i][2], acc[i][3]);
            float* cp = xfinal + (size_t)grow * 64 + c0;
            if (!FIRST) {
                float4 c = *(const float4*)cp;
                r.x += c.x; r.y += c.y; r.z += c.z; r.w += c.w;
            }
            *(float4*)cp = r;
        }
    }
}

// -- gin_fuse: t=gelu(z@W1+b1); o=t@W2+b2 (-> xout if NEXT); xfinal += o@Wf;
//    if NEXT: bfout = bf16(o @ Wn + bn)   (next pair's SAGE xt) --------------
template<bool NEXT>
__global__ __launch_bounds__(256) void gin_fuse(
    const float* __restrict__ z,
    const float* __restrict__ W1, const float* __restrict__ b1,
    const float* __restrict__ W2, const float* __restrict__ b2,
    const float* __restrict__ Wf,
    const float* __restrict__ Wn, const float* __restrict__ bn,
    float* __restrict__ xout, float* __restrict__ xfinal,
    unsigned short* __restrict__ bfout, int n)
{
    __shared__ __align__(16) float At[64][68];
    __shared__ __align__(16) float Ws[64][68];
    const int tid = threadIdx.x;
    const int tx = tid & 15, ty = tid >> 4;
    const int rowBase = blockIdx.x * 64;
    const int r0 = ty * 4, c0 = tx * 4;
    const int ty4 = ty * 4;

    {
        float4 R[4];
        #pragma unroll
        for (int i = 0; i < 4; ++i) {
            int grow = rowBase + ty4 + i;
            R[i] = make_float4(0.f, 0.f, 0.f, 0.f);
            if (grow < n) R[i] = *(const float4*)(z + (size_t)grow * 64 + tx * 4);
        }
        #pragma unroll
        for (int j = 0; j < 4; ++j) {
            float4 c = make_float4(((const float*)&R[0])[j],
                                   ((const float*)&R[1])[j],
                                   ((const float*)&R[2])[j],
                                   ((const float*)&R[3])[j]);
            *(float4*)&At[tx * 4 + j][ty4] = c;
        }
        #pragma unroll
        for (int i = 0; i < 4; ++i) {
            int v = tid + i * 256;
            int r = v >> 4, k4 = (v & 15) * 4;
            *(float4*)&Ws[r][k4] = *(const float4*)(W1 + r * 64 + k4);
        }
    }
    __syncthreads();

    float acc[4][4];
    #pragma unroll
    for (int j = 0; j < 4; ++j) {
        float bv = b1[c0 + j];
        #pragma unroll
        for (int i = 0; i < 4; ++i) acc[i][j] = bv;
    }
    #pragma unroll 16
    for (int k = 0; k < 64; ++k) {
        float4 av = *(const float4*)&At[k][r0];
        float4 wv = *(const float4*)&Ws[k][c0];
        float a4[4] = {av.x, av.y, av.z, av.w};
        float w4[4] = {wv.x, wv.y, wv.z, wv.w};
        #pragma unroll
        for (int i = 0; i < 4; ++i)
            #pragma unroll
            for (int j = 0; j < 4; ++j)
                acc[i][j] = fmaf(a4[i], w4[j], acc[i][j]);
    }

    // ---- GEMM2: gelu(acc) @ W2 + b2   (float4 transpose write)
    __syncthreads();
    #pragma unroll
    for (int j = 0; j < 4; ++j) {
        float4 c = make_float4(gelu_f(acc[0][j]), gelu_f(acc[1][j]),
                               gelu_f(acc[2][j]), gelu_f(acc[3][j]));
        *(float4*)&At[c0 + j][r0] = c;
    }
    #pragma unroll
    for (int i = 0; i < 4; ++i) {
        int v = tid + i * 256;
        int k = v >> 4, c4 = (v & 15) * 4;
        *(float4*)&Ws[k][c4] = *(const float4*)(W2 + k * 64 + c4);
    }
    __syncthreads();
    float acc2[4][4];
    #pragma unroll
    for (int j = 0; j < 4; ++j) {
        float bv = b2[c0 + j];
        #pragma unroll
        for (int i = 0; i < 4; ++i) acc2[i][j] = bv;
    }
    #pragma unroll 16
    for (int k = 0; k < 64; ++k) {
        float4 av = *(const float4*)&At[k][r0];
        float4 wv = *(const float4*)&Ws[k][c0];
        float a4[4] = {av.x, av.y, av.z, av.w};
        float w4[4] = {wv.x, wv.y, wv.z, wv.w};
        #pragma unroll
        for (int i = 0; i < 4; ++i)
            #pragma unroll
            for (int j = 0; j < 4; ++j)
                acc2[i][j] = fmaf(a4[i], w4[j], acc2[i][j]);
    }
    if (NEXT) {
        #pragma unroll
        for (int i = 0; i < 4; ++i) {
            int grow = rowBase + r0 + i;
            if (grow < n)
                *(float4*)(xout + (size_t)grow * 64 + c0) =
                    make_float4(acc2[i][0], acc2[i][1], acc2[i][2], acc2[i][3]);
        }
    }

    // ---- GEMM3: xfinal += acc2 @ Wf   (At <- acc2^T via float4; reused by GEMM4)
    __syncthreads();
    #pragma unroll
    for (int j = 0; j < 4; ++j) {
        float4 c = make_float4(acc2[0][j], acc2[1][j], acc2[2][j], acc2[3][j]);
        *(float4*)&At[c0 + j][r0] = c;
    }
    #pragma unroll
    for (int i = 0; i < 4; ++i) {
        int v = tid + i * 256;
        int k = v >> 4, c4 = (v & 15) * 4;
        *(float4*)&Ws[k][c4] = *(const float4*)(Wf + k * 64 + c4);
    }
    __syncthreads();
    float acc3[4][4];
    #pragma unroll
    for (int i = 0; i < 4; ++i)
        #pragma unroll
        for (int j = 0; j < 4; ++j) acc3[i][j] = 0.f;
    #pragma unroll 16
    for (int k = 0; k < 64; ++k) {
        float4 av = *(const float4*)&At[k][r0];
        float4 wv = *(const float4*)&Ws[k][c0];
        float a4[4] = {av.x, av.y, av.z, av.w};
        float w4[4] = {wv.x, wv.y, wv.z, wv.w};
        #pragma unroll
        for (int i = 0; i < 4; ++i)
            #pragma unroll
            for (int j = 0; j < 4; ++j)
                acc3[i][j] = fmaf(a4[i], w4[j], acc3[i][j]);
    }
    #pragma unroll
    for (int i = 0; i < 4; ++i) {
        int grow = rowBase + r0 + i;
        if (grow < n) {
            float* cp = xfinal + (size_t)grow * 64 + c0;
            float4 c = *(const float4*)cp;
            c.x += acc3[i][0]; c.y += acc3[i][1];
            c.z += acc3[i][2]; c.w += acc3[i][3];
            *(float4*)cp = c;
        }
    }

    if (NEXT) {
        // ---- GEMM4: bfout = bf16(acc2 @ Wn + bn); At still holds acc2^T
        __syncthreads();
        #pragma unroll
        for (int i = 0; i < 4; ++i) {
            int v = tid + i * 256;
            int k = v >> 4, c4 = (v & 15) * 4;
            *(float4*)&Ws[k][c4] = *(const float4*)(Wn + k * 64 + c4);
        }
        __syncthreads();
        float acc4[4][4];
        #pragma unroll
        for (int j = 0; j < 4; ++j) {
            float bv = bn[c0 + j];
            #pragma unroll
            for (int i = 0; i < 4; ++i) acc4[i][j] = bv;
        }
        #pragma unroll 16
        for (int k = 0; k < 64; ++k) {
            float4 av = *(const float4*)&At[k][r0];
            float4 wv = *(const float4*)&Ws[k][c0];
            float a4[4] = {av.x, av.y, av.z, av.w};
            float w4[4] = {wv.x, wv.y, wv.z, wv.w};
            #pragma unroll
            for (int i = 0; i < 4; ++i)
                #pragma unroll
                for (int j = 0; j < 4; ++j)
                    acc4[i][j] = fmaf(a4[i], w4[j], acc4[i][j]);
        }
        #pragma unroll
        for (int i = 0; i < 4; ++i) {
            int grow = rowBase + r0 + i;
            if (grow < n) {
                uint2 u;
                u.x = pack2bf(acc4[i][0], acc4[i][1]);
                u.y = pack2bf(acc4[i][2], acc4[i][3]);
                *(uint2*)(bfout + (size_t)grow * 64 + c0) = u;
            }
        }
    }
}

// ---------------- bucket-sorted CSR build ------------------------------------
__global__ void init_buckets(int* __restrict__ bucket_cursor, int Bn, int cap) {
    int t = threadIdx.x;
    if (t < Bn) bucket_cursor[t] = t * cap;
}

__global__ __launch_bounds__(256) void bucketA(
    const int* __restrict__ eidx, int* __restrict__ bucket_cursor,
    uint2* __restrict__ inter, int E)
{
    __shared__ int cnt[256], lo[256], cur[256], garr[256];
    __shared__ int tot_s;
    __shared__ uint2 stage[4096];
    const int tid = threadIdx.x;
    cnt[tid] = 0;
    __syncthreads();

    const int base = blockIdx.x * 4096;
    int pay[16], dfull[16];
    #pragma unroll
    for (int i = 0; i < 16; ++i) {
        int e = base + i * 256 + tid;
        dfull[i] = -1;
        if (e < E) {
            int s  = __builtin_nontemporal_load(eidx + e * 3 + 0);
            int d  = __builtin_nontemporal_load(eidx + e * 3 + 1);
            int sg = __builtin_nontemporal_load(eidx + e * 3 + 2);
            if (sg < 0) s |= 0x80000000;
            pay[i] = s;
            dfull[i] = d;
            atomicAdd(&cnt[d >> NBSHIFT], 1);
        }
    }
    __syncthreads();

    lo[tid] = cnt[tid];
    __syncthreads();
    for (int off = 1; off < 256; off <<= 1) {
        int t = (tid >= off) ? lo[tid - off] : 0;
        __syncthreads();
        lo[tid] += t;
        __syncthreads();
    }
    if (tid == 255) tot_s = lo[255];
    int excl = lo[tid] - cnt[tid];
    __syncthreads();
    lo[tid] = excl;
    cur[tid] = 0;
    if (cnt[tid] > 0) garr[tid] = atomicAdd(bucket_cursor + tid, cnt[tid]);
    __syncthreads();

    #pragma unroll
    for (int i = 0; i < 16; ++i) {
        if (dfull[i] >= 0) {
            int k = dfull[i] >> NBSHIFT;
            int r = atomicAdd(&cur[k], 1);
            stage[lo[k] + r] = make_uint2((unsigned)pay[i], (unsigned)dfull[i]);
        }
    }
    __syncthreads();

    const int tot = tot_s;
    for (int i = tid; i < tot; i += 256) {
        uint2 en = stage[i];
        int k = (int)(en.y >> NBSHIFT);
        inter[garr[k] + (i - lo[k])] = en;
    }
}

__global__ __launch_bounds__(256) void bucketB1(
    const uint2* __restrict__ inter, const int* __restrict__ bucket_cursor,
    int* __restrict__ deg_i, int cap, int n)
{
    __shared__ int cnt[NBSIZE];
    const int b = blockIdx.x, tid = threadIdx.x;
    cnt[tid] = 0; cnt[tid + 256] = 0;
    __syncthreads();
    const int base = b * cap;
    const int len = bucket_cursor[b] - base;
    for (int i = tid; i < len; i += 256)
        atomicAdd(&cnt[inter[base + i].y & (NBSIZE - 1)], 1);
    __syncthreads();
    const int nb0 = b << NBSHIFT;
    if (nb0 + tid < n)       deg_i[nb0 + tid]       = cnt[tid];
    if (nb0 + 256 + tid < n) deg_i[nb0 + 256 + tid] = cnt[256 + tid];
}

__global__ __launch_bounds__(256) void bucketB2(
    const uint2* __restrict__ inter, const int* __restrict__ bucket_cursor,
    const int* __restrict__ row_ptr, int* __restrict__ payload, int cap, int n)
{
    __shared__ int cur[NBSIZE];
    const int b = blockIdx.x, tid = threadIdx.x;
    const int nb0 = b << NBSHIFT;
    cur[tid]       = (nb0 + tid < n)       ? row_ptr[nb0 + tid]       : 0;
    cur[tid + 256] = (nb0 + 256 + tid < n) ? row_ptr[nb0 + 256 + tid] : 0;
    __syncthreads();
    const int base = b * cap;
    const int len = bucket_cursor[b] - base;
    for (int i = tid; i < len; i += 256) {
        uint2 en = inter[base + i];
        int pos = atomicAdd(&cur[en.y & (NBSIZE - 1)], 1);
        payload[pos] = (int)en.x;
    }
}

// ---------------- scans ------------------------------------------------------
__global__ __launch_bounds__(256) void scan1(
    const int* __restrict__ deg_i, int* __restrict__ blocksum, int n, int chunk)
{
    int b = blockIdx.x;
    int lo = b * chunk, hi = min(lo + chunk, n);
    int s = 0;
    for (int i = lo + (int)threadIdx.x; i < hi; i += 256) s += deg_i[i];
    #pragma unroll
    for (int off = 32; off; off >>= 1) s += __shfl_xor(s, off, 64);
    __shared__ int ws[4];
    if ((threadIdx.x & 63) == 0) ws[threadIdx.x >> 6] = s;
    __syncthreads();
    if (threadIdx.x == 0) blocksum[b] = ws[0] + ws[1] + ws[2] + ws[3];
}

__global__ __launch_bounds__(256) void scan2(
    const int* __restrict__ blocksum, int* __restrict__ blockoff,
    int* __restrict__ row_ptr_n)
{
    int tid = threadIdx.x, lane = tid & 63, wid = tid >> 6;
    int orig = blocksum[tid];
    int v = orig;
    #pragma unroll
    for (int off = 1; off < 64; off <<= 1) {
        int t = __shfl_up(v, off, 64);
        if (lane >= off) v += t;
    }
    __shared__ int wt[4];
    if (lane == 63) wt[wid] = v;
    __syncthreads();
    int woff = 0;
    for (int w = 0; w < wid; ++w) woff += wt[w];
    blockoff[tid] = woff + v - orig;
    if (tid == 255) *row_ptr_n = woff + v;
}

__global__ __launch_bounds__(256) void scan3(
    const int* __restrict__ deg_i, const int* __restrict__ blockoff,
    int* __restrict__ row_ptr, float* __restrict__ rdeg, int n, int chunk)
{
    int b = blockIdx.x;
    int lo = b * chunk, hi = min(lo + chunk, n);
    int carry = blockoff[b];
    int tid = threadIdx.x, lane = tid & 63, wid = tid >> 6;
    __shared__ int wt[4];
    for (int base = lo; base < hi; base += 256) {
        int i = base + tid;
        int orig = (i < hi) ? deg_i[i] : 0;
        int v = orig;
        #pragma unroll
        for (int off = 1; off < 64; off <<= 1) {
            int t = __shfl_up(v, off, 64);
            if (lane >= off) v += t;
        }
        if (lane == 63) wt[wid] = v;
        __syncthreads();
        int woff = 0;
        for (int w = 0; w < wid; ++w) woff += wt[w];
        int tot = wt[0] + wt[1] + wt[2] + wt[3];
        int excl = carry + woff + (v - orig);
        if (i < hi) {
            row_ptr[i] = excl;
            rdeg[i]    = 1.0f / ((float)orig + 1.0f);
        }
        carry += tot;
        __syncthreads();
    }
}

// ------- gather R18: 8 nodes/wave (8-lane group per node), lane-private
//         accumulation, uniform trip count; row loads software-pipelined one
//         quad ahead (u=current quad, v=next quad in flight -> 8 rows/wave
//         group pair in flight steady-state). No nontemporal hints.
__device__ __forceinline__ void accum8(float* a, uint4 u, float s) {
    a[0] = fmaf(__uint_as_float(u.x << 16),          s, a[0]);
    a[1] = fmaf(__uint_as_float(u.x & 0xffff0000u),  s, a[1]);
    a[2] = fmaf(__uint_as_float(u.y << 16),          s, a[2]);
    a[3] = fmaf(__uint_as_float(u.y & 0xffff0000u),  s, a[3]);
    a[4] = fmaf(__uint_as_float(u.z << 16),          s, a[4]);
    a[5] = fmaf(__uint_as_float(u.z & 0xffff0000u),  s, a[5]);
    a[6] = fmaf(__uint_as_float(u.w << 16),          s, a[6]);
    a[7] = fmaf(__uint_as_float(u.w & 0xffff0000u),  s, a[7]);
}

template<bool SAGE>
__global__ __launch_bounds__(256) void gather64(
    const int* __restrict__ row_ptr, const int* __restrict__ payload,
    const unsigned short* __restrict__ valb, const float* __restrict__ xprev,
    const float* __restrict__ rdeg, float* __restrict__ out,
    float* __restrict__ colsum, float* __restrict__ colsumsq, int n)
{
    const int tid  = threadIdx.x;
    const int lane = tid & 63;
    const int j8   = lane & 7;           // col sub-slot
    const int c0   = j8 * 8;             // cols [c0, c0+8)
    const int wid  = tid >> 6;
    const int gg0  = (blockIdx.x * 256 + tid) >> 3;   // global group id
    const int ng   = (gridDim.x * 256) >> 3;          // total groups

    float st[8], st2[8];
    if (SAGE) {
        #pragma unroll
        for (int k = 0; k < 8; ++k) { st[k] = 0.f; st2[k] = 0.f; }
    }

    for (int node = gg0; __any(node < n); node += ng) {
        const bool active  = node < n;
        const int  selfrow = active ? node : 0;
        const int  beg     = active ? row_ptr[node]     : 0;
        const int  end     = active ? row_ptr[node + 1] : 0;

        // wave-uniform trip count = max over the 8 groups
        int t = (end - beg + 3) >> 2;
        t = max(t, __shfl_xor(t, 8, 64));
        t = max(t, __shfl_xor(t, 16, 64));
        t = max(t, __shfl_xor(t, 32, 64));

        float a[8];
        #pragma unroll
        for (int k = 0; k < 8; ++k) a[k] = 0.f;

        // ---- prologue: quad 0 rows issued, quad 1 payload issued
        bool w0 = beg + 0 < end, w1 = beg + 1 < end;
        bool w2 = beg + 2 < end, w3 = beg + 3 < end;
        int q0 = w0 ? payload[beg + 0] : 0;
        int q1 = w1 ? payload[beg + 1] : 0;
        int q2 = w2 ? payload[beg + 2] : 0;
        int q3 = w3 ? payload[beg + 3] : 0;
        uint4 u0 = *(const uint4*)(valb + (size_t)(w0 ? (q0 & 0x7fffffff) : selfrow) * 64 + c0);
        uint4 u1 = *(const uint4*)(valb + (size_t)(w1 ? (q1 & 0x7fffffff) : selfrow) * 64 + c0);
        uint4 u2 = *(const uint4*)(valb + (size_t)(w2 ? (q2 & 0x7fffffff) : selfrow) * 64 + c0);
        uint4 u3 = *(const uint4*)(valb + (size_t)(w3 ? (q3 & 0x7fffffff) : selfrow) * 64 + c0);
        float s0 = w0 ? ((SAGE && q0 < 0) ? -1.f : 1.f) : 0.f;
        float s1 = w1 ? ((SAGE && q1 < 0) ? -1.f : 1.f) : 0.f;
        float s2 = w2 ? ((SAGE && q2 < 0) ? -1.f : 1.f) : 0.f;
        float s3 = w3 ? ((SAGE && q3 < 0) ? -1.f : 1.f) : 0.f;
        int np0 = (beg + 4 < end) ? payload[beg + 4] : 0;
        int np1 = (beg + 5 < end) ? payload[beg + 5] : 0;
        int np2 = (beg + 6 < end) ? payload[beg + 6] : 0;
        int np3 = (beg + 7 < end) ? payload[beg + 7] : 0;

        for (int it = 0; it < t; ++it) {
            // issue NEXT quad's rows (overlaps with consuming current quad)
            const int ib = beg + ((it + 1) << 2);
            const bool x0 = ib + 0 < end, x1 = ib + 1 < end;
            const bool x2 = ib + 2 < end, x3 = ib + 3 < end;
            uint4 v0 = *(const uint4*)(valb + (size_t)(x0 ? (np0 & 0x7fffffff) : selfrow) * 64 + c0);
            uint4 v1 = *(const uint4*)(valb + (size_t)(x1 ? (np1 & 0x7fffffff) : selfrow) * 64 + c0);
            uint4 v2 = *(const uint4*)(valb + (size_t)(x2 ? (np2 & 0x7fffffff) : selfrow) * 64 + c0);
            uint4 v3 = *(const uint4*)(valb + (size_t)(x3 ? (np3 & 0x7fffffff) : selfrow) * 64 + c0);
            const float z0 = x0 ? ((SAGE && np0 < 0) ? -1.f : 1.f) : 0.f;
            const float z1 = x1 ? ((SAGE && np1 < 0) ? -1.f : 1.f) : 0.f;
            const float z2 = x2 ? ((SAGE && np2 < 0) ? -1.f : 1.f) : 0.f;
            const float z3 = x3 ? ((SAGE && np3 < 0) ? -1.f : 1.f) : 0.f;

            // prefetch payload for quad it+2
            const int fb = beg + ((it + 2) << 2);
            np0 = (fb + 0 < end) ? payload[fb + 0] : 0;
            np1 = (fb + 1 < end) ? payload[fb + 1] : 0;
            np2 = (fb + 2 < end) ? payload[fb + 2] : 0;
            np3 = (fb + 3 < end) ? payload[fb + 3] : 0;

            // consume current quad (waits only on u*, v* stay in flight)
            accum8(a, u0, s0);
            accum8(a, u1, s1);
            accum8(a, u2, s2);
            accum8(a, u3, s3);

            u0 = v0; u1 = v1; u2 = v2; u3 = v3;
            s0 = z0; s1 = z1; s2 = z2; s3 = z3;
        }

        // self row (xt for SAGE, x for GIN)
        uint4 us = *(const uint4*)(valb + (size_t)selfrow * 64 + c0);
        accum8(a, us, 1.f);

        if (SAGE) {
            const float rd = active ? rdeg[node] : 0.f;
            float4 xp0 = *(const float4*)(xprev + (size_t)selfrow * 64 + c0);
            float4 xp1 = *(const float4*)(xprev + (size_t)selfrow * 64 + c0 + 4);
            float xp[8] = {xp0.x, xp0.y, xp0.z, xp0.w,
                           xp1.x, xp1.y, xp1.z, xp1.w};
            float h[8];
            #pragma unroll
            for (int k = 0; k < 8; ++k) h[k] = fmaf(a[k], rd, xp[k]);
            if (active) {
                #pragma unroll
                for (int k = 0; k < 8; ++k) {
                    st[k]  += h[k];
                    st2[k] += h[k] * h[k];
                }
                *(float4*)(out + (size_t)node * 64 + c0) =
                    make_float4(h[0], h[1], h[2], h[3]);
                *(float4*)(out + (size_t)node * 64 + c0 + 4) =
                    make_float4(h[4], h[5], h[6], h[7]);
            }
        } else {
            if (active) {
                *(float4*)(out + (size_t)node * 64 + c0) =
                    make_float4(a[0], a[1], a[2], a[3]);
                *(float4*)(out + (size_t)node * 64 + c0 + 4) =
                    make_float4(a[4], a[5], a[6], a[7]);
            }
        }
    }

    if (SAGE) {
        // fold the 8 groups (lane-xor 8/16/32); each j8-class ends identical
        #pragma unroll
        for (int k = 0; k < 8; ++k) {
            st[k]  += __shfl_xor(st[k], 8, 64);
            st[k]  += __shfl_xor(st[k], 16, 64);
            st[k]  += __shfl_xor(st[k], 32, 64);
            st2[k] += __shfl_xor(st2[k], 8, 64);
            st2[k] += __shfl_xor(st2[k], 16, 64);
            st2[k] += __shfl_xor(st2[k], 32, 64);
        }
        __shared__ float sh[2][4][64];
        if (lane < 8) {
            #pragma unroll
            for (int k = 0; k < 8; ++k) {
                sh[0][wid][c0 + k] = st[k];
                sh[1][wid][c0 + k] = st2[k];
            }
        }
        __syncthreads();
        if (tid < 64) {
            float a_ = sh[0][0][tid] + sh[0][1][tid] + sh[0][2][tid] + sh[0][3][tid];
            float b_ = sh[1][0][tid] + sh[1][1][tid] + sh[1][2][tid] + sh[1][3][tid];
            atomicAdd(colsum + tid, a_);
            atomicAdd(colsumsq + tid, b_);
        }
    }
}

// ---------------- readout stage 1: H = relu(LN(x @ W1 + b1)) -----------------
__global__ __launch_bounds__(256) void readout1(
    const float* __restrict__ xf, const float* __restrict__ W1,
    const float* __restrict__ b1, const float* __restrict__ g1,
    const float* __restrict__ bt1, float* __restrict__ H, int n)
{
    __shared__ __align__(16) float At[64][68];
    __shared__ __align__(16) float Ws[64][132];
    const int tid = threadIdx.x;
    const int tx = tid & 15, ty = tid >> 4;
    const int rowBase = blockIdx.x * 64;
    const int ty4 = ty * 4;

    {
        float4 R[4];
        #pragma unroll
        for (int i = 0; i < 4; ++i) {
            int grow = rowBase + ty4 + i;
            R[i] = make_float4(0.f, 0.f, 0.f, 0.f);
            if (grow < n) R[i] = *(const float4*)(xf + (size_t)grow * 64 + tx * 4);
        }
        #pragma unroll
        for (int j = 0; j < 4; ++j) {
            float4 c = make_float4(((const float*)&R[0])[j],
                                   ((const float*)&R[1])[j],
                                   ((const float*)&R[2])[j],
                                   ((const float*)&R[3])[j]);
            *(float4*)&At[tx * 4 + j][ty4] = c;
        }
    }
    #pragma unroll
    for (int i = 0; i < 8; ++i) {
        int v = tid + i * 256;
        int k = v >> 5, c4 = (v & 31) * 4;
        *(float4*)&Ws[k][c4] = *(const float4*)(W1 + k * 128 + c4);
    }
    __syncthreads();

    const int r0 = ty * 4, c0 = tx * 8;
    float acc[4][8];
    #pragma unroll
    for (int j = 0; j < 8; ++j) {
        float bv = b1[c0 + j];
        #pragma unroll
        for (int i = 0; i < 4; ++i) acc[i][j] = bv;
    }
    #pragma unroll 8
    for (int k = 0; k < 64; ++k) {
        float4 av = *(const float4*)&At[k][r0];
        float4 w0 = *(const float4*)&Ws[k][c0];
        float4 w1v = *(const float4*)&Ws[k][c0 + 4];
        float a4[4] = {av.x, av.y, av.z, av.w};
        float w8[8] = {w0.x, w0.y, w0.z, w0.w, w1v.x, w1v.y, w1v.z, w1v.w};
        #pragma unroll
        for (int i = 0; i < 4; ++i)
            #pragma unroll
            for (int j = 0; j < 8; ++j)
                acc[i][j] = fmaf(a4[i], w8[j], acc[i][j]);
    }

    float gj[8], bj[8];
    #pragma unroll
    for (int j = 0; j < 8; ++j) { gj[j] = g1[c0 + j]; bj[j] = bt1[c0 + j]; }
    #pragma unroll
    for (int i = 0; i < 4; ++i) {
        int grow = rowBase + r0 + i;
        float s = 0.f, s2 = 0.f;
        #pragma unroll
        for (int j = 0; j < 8; ++j) { s += acc[i][j]; s2 += acc[i][j] * acc[i][j]; }
        #pragma unroll
        for (int off = 8; off; off >>= 1) {
            s  += __shfl_xor(s, off, 16);
            s2 += __shfl_xor(s2, off, 16);
        }
        float mean = s * (1.f / 128.f);
        float var  = s2 * (1.f / 128.f) - mean * mean;
        float rstd = rsqrtf(var + 1e-5f);
        float o[8];
        #pragma unroll
        for (int j = 0; j < 8; ++j)
            o[j] = fmaxf(fmaf((acc[i][j] - mean) * rstd, gj[j], bj[j]), 0.f);
        if (grow < n) {
            *(float4*)(H + (size_t)grow * 128 + c0)     = make_float4(o[0], o[1], o[2], o[3]);
            *(float4*)(H + (size_t)grow * 128 + c0 + 4) = make_float4(o[4], o[5], o[6], o[7]);
        }
    }
}

// ------- readout stage 2: prob = sigmoid(relu(LN(H @ W2 + b2)) @ W3 + b3) ----
__global__ __launch_bounds__(256) void readout2(
    const float* __restrict__ H, const float* __restrict__ W2,
    const float* __restrict__ b2, const float* __restrict__ g2,
    const float* __restrict__ bt2, const float* __restrict__ W3,
    const float* __restrict__ b3, float* __restrict__ prob, int n)
{
    __shared__ __align__(16) float Ht[64][68];
    __shared__ __align__(16) float Ws[64][132];
    const int tid = threadIdx.x;
    const int tx = tid & 15, ty = tid >> 4;
    const int rowBase = blockIdx.x * 64;
    const int r0 = ty * 4, c0 = tx * 8;
    const int ty4 = ty * 4;

    float acc[4][8];
    #pragma unroll
    for (int j = 0; j < 8; ++j) {
        float bv = b2[c0 + j];
        #pragma unroll
        for (int i = 0; i < 4; ++i) acc[i][j] = bv;
    }

    for (int kc = 0; kc < 2; ++kc) {
        if (kc) __syncthreads();
        {
            float4 R[4];
            #pragma unroll
            for (int i = 0; i < 4; ++i) {
                int grow = rowBase + ty4 + i;
                R[i] = make_float4(0.f, 0.f, 0.f, 0.f);
                if (grow < n)
                    R[i] = *(const float4*)(H + (size_t)grow * 128 + kc * 64 + tx * 4);
            }
            #pragma unroll
            for (int j = 0; j < 4; ++j) {
                float4 c = make_float4(((const float*)&R[0])[j],
                                       ((const float*)&R[1])[j],
                                       ((const float*)&R[2])[j],
                                       ((const float*)&R[3])[j]);
                *(float4*)&Ht[tx * 4 + j][ty4] = c;
            }
        }
        #pragma unroll
        for (int i = 0; i < 8; ++i) {
            int v = tid + i * 256;
            int k = v >> 5, c4 = (v & 31) * 4;
            *(float4*)&Ws[k][c4] = *(const float4*)(W2 + (kc * 64 + k) * 128 + c4);
        }
        __syncthreads();
        #pragma unroll 8
        for (int k = 0; k < 64; ++k) {
            float4 av = *(const float4*)&Ht[k][r0];
            float4 w0 = *(const float4*)&Ws[k][c0];
            float4 w1v = *(const float4*)&Ws[k][c0 + 4];
            float a4[4] = {av.x, av.y, av.z, av.w};
            float w8[8] = {w0.x, w0.y, w0.z, w0.w, w1v.x, w1v.y, w1v.z, w1v.w};
            #pragma unroll
            for (int i = 0; i < 4; ++i)
                #pragma unroll
                for (int j = 0; j < 8; ++j)
                    acc[i][j] = fmaf(a4[i], w8[j], acc[i][j]);
        }
    }

    float gj[8], bj[8], w3[8];
    #pragma unroll
    for (int j = 0; j < 8; ++j) {
        gj[j] = g2[c0 + j]; bj[j] = bt2[c0 + j]; w3[j] = W3[c0 + j];
    }
    const float bias3 = b3[0];
    #pragma unroll
    for (int i = 0; i < 4; ++i) {
        int grow = rowBase + r0 + i;
        float s = 0.f, s2 = 0.f;
        #pragma unroll
        for (int j = 0; j < 8; ++j) { s += acc[i][j]; s2 += acc[i][j] * acc[i][j]; }
        #pragma unroll
        for (int off = 8; off; off >>= 1) {
            s  += __shfl_xor(s, off, 16);
            s2 += __shfl_xor(s2, off, 16);
        }
        float mean = s * (1.f / 128.f);
        float var  = s2 * (1.f / 128.f) - mean * mean;
        float rstd = rsqrtf(var + 1e-5f);
        float d = 0.f;
        #pragma unroll
        for (int j = 0; j < 8; ++j) {
            float v = fmaxf(fmaf((acc[i][j] - mean) * rstd, gj[j], bj[j]), 0.f);
            d = fmaf(v, w3[j], d);
        }
        #pragma unroll
        for (int off = 8; off; off >>= 1) d += __shfl_xor(d, off, 16);
        if (tx == 0 && grow < n)
            prob[grow] = 1.f / (1.f + expf(-(d + bias3)));
    }
}

// ---------------------------------------------------------------------------
extern "C" void kernel_launch(void* const* d_in, const int* in_sizes, int n_in,
                              void* d_out, int out_size, void* d_ws, size_t ws_size,
                              hipStream_t stream)
{
    const float* init_emb = (const float*)d_in[0];
    const int*   eidx     = (const int*)d_in[1];
    const float* rate_b   = (const float*)d_in[2];
    const float* sage_W   = (const float*)d_in[3];
    const float* sage_b   = (const float*)d_in[4];
    const float* norm_w   = (const float*)d_in[5];
    const float* norm_b   = (const float*)d_in[6];
    const float* rs_w     = (const float*)d_in[7];
    const float* rs_b     = (const float*)d_in[8];
    const float* rb_w     = (const float*)d_in[9];
    const float* rb_b     = (const float*)d_in[10];
    const float* gin_W1   = (const float*)d_in[11];
    const float* gin_b1   = (const float*)d_in[12];
    const float* gin_W2   = (const float*)d_in[13];
    const float* gin_b2   = (const float*)d_in[14];
    const float* fuse_W   = (const float*)d_in[15];
    const float* fuse_b   = (const float*)d_in[16];
    const float* ro_W1    = (const float*)d_in[17];
    const float* ro_b1    = (const float*)d_in[18];
    const float* ln1_g    = (const float*)d_in[19];
    const float* ln1_b    = (const float*)d_in[20];
    const float* ro_W2    = (const float*)d_in[21];
    const float* ro_b2    = (const float*)d_in[22];
    const float* ln2_g    = (const float*)d_in[23];
    const float* ln2_b    = (const float*)d_in[24];
    const float* ro_W3    = (const float*)d_in[25];
    const float* ro_b3    = (const float*)d_in[26];

    const int N = in_sizes[0] / 64;
    const int E = in_sizes[1] / 3;
    const size_t nf = (size_t)N * 64;

    float* bufA  = (float*)d_ws;             // H region (with bufB) at readout
    float* bufB  = bufA + nf;
    float* bufC  = bufB + nf;
    unsigned short* bfbuf = (unsigned short*)(bufC + nf);  // nf bf16
    float* rdeg  = (float*)(bfbuf + nf);     // N floats
    float* stats = rdeg + N;                 // 3 x (colsum64|colsumsq64|pad)
    int*   row_ptr  = (int*)(stats + 3 * 256);   // N+1
    int*   deg_i    = row_ptr + (N + 1);         // N
    int*   blocksum = deg_i + N;                 // 256
    int*   blockoff = blocksum + 256;            // 256
    int*   bucket_cursor = blockoff + 256;       // <=256
    int*   payload  = bucket_cursor + 256;       // E
    uint2* inter    = (uint2*)bufC;              // aliases bufC (dead until p=1)

    float* xfinal = (float*)d_out;           // N x 64
    float* prob   = xfinal + nf;             // N
    float* H      = bufA;                    // N x 128 (bufA+bufB)

    const int gemm_blocks = (N + 63) / 64;
    const int gather_blocks = 2048;
    const int chunk  = (N + 255) / 256;
    const float inv_n = 1.0f / (float)N;

    const int Bn   = (N + NBSIZE - 1) / NBSIZE;
    const int meanb = (E + Bn - 1) / Bn;
    const int cap  = meanb + meanb / 8 + 64;
    const int ablocks = (E + 4095) / 4096;

    // ---- CSR build (bucket-sorted, deterministic) ----
    hipMemsetAsync(stats, 0, 3 * 256 * sizeof(float), stream);
    init_buckets<<<1, 256, 0, stream>>>(bucket_cursor, Bn, cap);
    bucketA<<<ablocks, 256, 0, stream>>>(eidx, bucket_cursor, inter, E);
    bucketB1<<<Bn, 256, 0, stream>>>(inter, bucket_cursor, deg_i, cap, N);
    scan1<<<256, 256, 0, stream>>>(deg_i, blocksum, N, chunk);
    scan2<<<1, 256, 0, stream>>>(blocksum, blockoff, row_ptr + N);
    scan3<<<256, 256, 0, stream>>>(deg_i, blockoff, row_ptr, rdeg, N, chunk);
    bucketB2<<<Bn, 256, 0, stream>>>(inter, bucket_cursor, row_ptr, payload, cap, N);

    for (int p = 0; p < 3; ++p) {
        const float* Xp = (p == 0) ? init_emb : (p == 1 ? (const float*)bufB : (const float*)bufC);
        float* B2p = (p == 1) ? bufC : bufB;
        float* cs = stats + p * 256;

        // 1. bfbuf = bf16(Xp @ W + b): explicit GEMM only for p=0; pairs 1,2
        //    get bfbuf from the previous gin_fuse's fused GEMM4.
        if (p == 0)
            gemm64<<<gemm_blocks, 256, 0, stream>>>(
                Xp, sage_W, sage_b, bfbuf, N);
        // 2. B2p = (xt + sum sign*xt[src]) * rdeg + Xp ; column stats
        gather64<true><<<gather_blocks, 256, 0, stream>>>(
            row_ptr, payload, bfbuf, Xp, rdeg, B2p, cs, cs + 64, N);
        // 3. bfbuf = bf16(gelu(norm(h))); xfinal (+)= x @ fuse_W[2p]
        if (p == 0)
            act_fuse<true><<<gemm_blocks, 256, 0, stream>>>(
                B2p, cs, cs + 64,
                norm_w + p * 64, norm_b + p * 64, rs_w + p * 64, rs_b + p * 64,
                rb_w + p * 64, rb_b + p * 64, rate_b, inv_n,
                fuse_W, fuse_b, bfbuf, xfinal, N);
        else
            act_fuse<false><<<gemm_blocks, 256, 0, stream>>>(
                B2p, cs, cs + 64,
                norm_w + p * 64, norm_b + p * 64, rs_w + p * 64, rs_b + p * 64,
                rb_w + p * 64, rb_b + p * 64, rate_b, inv_n,
                fuse_W + (2 * p) * 4096, nullptr, bfbuf, xfinal, N);
        // 4. B2p = x + sum x[src]   (z, from bf16 x copy)
        gather64<false><<<gather_blocks, 256, 0, stream>>>(
            row_ptr, payload, bfbuf, nullptr, nullptr, B2p, nullptr, nullptr, N);
        // 5. gin: B2p = gelu(z@W1+b1)@W2+b2 ; xfinal += B2p@fuse ;
        //    p<2: bfbuf = bf16(B2p @ sage_W[p+1] + sage_b[p+1])
        if (p < 2)
            gin_fuse<true><<<gemm_blocks, 256, 0, stream>>>(
                B2p, gin_W1 + p * 4096, gin_b1 + p * 64,
                gin_W2 + p * 4096, gin_b2 + p * 64,
                fuse_W + (2 * p + 1) * 4096,
                sage_W + (p + 1) * 4096, sage_b + (p + 1) * 64,
                B2p, xfinal, bfbuf, N);
        else
            gin_fuse<false><<<gemm_blocks, 256, 0, stream>>>(
                B2p, gin_W1 + p * 4096, gin_b1 + p * 64,
                gin_W2 + p * 4096, gin_b2 + p * 64,
                fuse_W + (2 * p + 1) * 4096,
                nullptr, nullptr, B2p, xfinal, nullptr, N);
    }

    // ---- readout ----
    readout1<<<gemm_blocks, 256, 0, stream>>>(
        xfinal, ro_W1, ro_b1, ln1_g, ln1_b, H, N);
    readout2<<<gemm_blocks, 256, 0, stream>>>(
        H, ro_W2, ro_b2, ln2_g, ln2_b, ro_W3, ro_b3, prob, N);
}